// Round 7
// baseline (24.315 us; speedup 1.0000x reference)
//
#include <hip/hip_runtime.h>

#define NG    2048
#define IMG_W 128
#define IMG_H 128
#define NPIX  (IMG_W * IMG_H)
#define KCAP  768           // per-tile record capacity (observed K ~120 max)

// ---------------------------------------------------------------------------
// ONE kernel, block = one 8x8 tile (256 blocks x 256 threads, 1 block/CU).
//  P2 (wave 0, lanes 0-7): radii-only fp64 chain for the block's 8 owned
//      gaussians (ceil() discontinuity -> fp64). Other waves run ahead.
//  P3 (all threads, 8 iters): full fp32 preprocess of ALL 2048 gaussians +
//      conservative r2cull tile test -> append passing records to LDS.
//      (No prefilter: 8 uniform iterations beat a prefilter pass + the
//       central-tile candidate imbalance it feeds.)
//  P4: exact stable rank by (z_from_fp64, idx) == jnp.argsort order on the
//      subset, then PHYSICAL reorder into sorted LDS (kills the dependent
//      perm->recs double-LDS-read in the composite loop).
//  P5: 4-wave depth-segment compositing, 3x ds_read_b128 per record
//      (sequential, broadcast), exact segment combination.
// ---------------------------------------------------------------------------
__global__ __launch_bounds__(256) void fused_raster_kernel(
    const float* __restrict__ means,
    const float* __restrict__ opac,
    const float* __restrict__ cols,
    const float* __restrict__ scales,
    const float* __restrict__ rots,
    const float* __restrict__ vm4,
    const float* __restrict__ bg,
    float* __restrict__ out)
{
    __shared__ __align__(16) float recs[KCAP][12];  // mx,my,A,B,C,op,z,r,g,b,-,-
    __shared__ __align__(16) float srec[KCAP][12];  // physically depth-sorted
    __shared__ float pz[KCAP];
    __shared__ unsigned short pid[KCAP];
    __shared__ float comb[4 * 64 * 5];
    __shared__ int cntK;

    int tid  = threadIdx.x;
    int tile = blockIdx.x;
    int x0 = (tile & 15) * 8;
    int y0 = (tile >> 4) * 8;
    float x0f = (float)x0,       y0f = (float)y0;
    float x1f = (float)(x0 + 7), y1f = (float)(y0 + 7);

    if (tid == 0) cntK = 0;
    __syncthreads();

    float fR00 = vm4[0], fR01 = vm4[1], fR02 = vm4[2],  ft0 = vm4[3];
    float fR10 = vm4[4], fR11 = vm4[5], fR12 = vm4[6],  ft1 = vm4[7];
    float fR20 = vm4[8], fR21 = vm4[9], fR22 = vm4[10], ft2 = vm4[11];

    // ---- P2: radii-only fp64 chain, 8 owned gaussians (wave 0 only) ----
    if (tid < 8) {
        int i = tile * 8 + tid;
        double R00 = vm4[0], R01 = vm4[1], R02 = vm4[2];
        double R10 = vm4[4], R11 = vm4[5], R12 = vm4[6];
        double R20 = vm4[8], R21 = vm4[9], R22 = vm4[10];
        double m0 = means[3*i+0], m1 = means[3*i+1], m2 = means[3*i+2];
        double x = R00*m0 + R01*m1 + R02*m2 + (double)vm4[3];
        double y = R10*m0 + R11*m1 + R12*m2 + (double)vm4[7];
        double z = R20*m0 + R21*m1 + R22*m2 + (double)vm4[11];
        double zc   = fmax(z, 1e-4);
        double invz = 1.0 / zc;
        double tx = fmin(0.65, fmax(-0.65, x * invz)) * zc;
        double ty = fmin(0.65, fmax(-0.65, y * invz)) * zc;
        double J00 = 128.0 * invz, J02 = -128.0 * tx * invz * invz;
        double J11 = 128.0 * invz, J12 = -128.0 * ty * invz * invz;
        double qw = rots[4*i+0], qx = rots[4*i+1], qy = rots[4*i+2], qz = rots[4*i+3];
        double qn = 1.0 / sqrt(qw*qw + qx*qx + qy*qy + qz*qz);
        qw *= qn; qx *= qn; qy *= qn; qz *= qn;
        double Rg00 = 1.0-2.0*(qy*qy+qz*qz), Rg01 = 2.0*(qx*qy-qw*qz), Rg02 = 2.0*(qx*qz+qw*qy);
        double Rg10 = 2.0*(qx*qy+qw*qz), Rg11 = 1.0-2.0*(qx*qx+qz*qz), Rg12 = 2.0*(qy*qz-qw*qx);
        double Rg20 = 2.0*(qx*qz-qw*qy), Rg21 = 2.0*(qy*qz+qw*qx), Rg22 = 1.0-2.0*(qx*qx+qy*qy);
        double s0 = scales[3*i+0], s1 = scales[3*i+1], s2 = scales[3*i+2];
        double M00 = Rg00*s0, M01 = Rg01*s1, M02 = Rg02*s2;
        double M10 = Rg10*s0, M11 = Rg11*s1, M12 = Rg12*s2;
        double M20 = Rg20*s0, M21 = Rg21*s1, M22 = Rg22*s2;
        double S00 = M00*M00+M01*M01+M02*M02;
        double S01 = M00*M10+M01*M11+M02*M12;
        double S02 = M00*M20+M01*M21+M02*M22;
        double S11 = M10*M10+M11*M11+M12*M12;
        double S12 = M10*M20+M11*M21+M12*M22;
        double S22 = M20*M20+M21*M21+M22*M22;
        double Ta0 = J00*R00+J02*R20, Ta1 = J00*R01+J02*R21, Ta2 = J00*R02+J02*R22;
        double Tb0 = J11*R10+J12*R20, Tb1 = J11*R11+J12*R21, Tb2 = J11*R12+J12*R22;
        double Ua0 = Ta0*S00+Ta1*S01+Ta2*S02;
        double Ua1 = Ta0*S01+Ta1*S11+Ta2*S12;
        double Ua2 = Ta0*S02+Ta1*S12+Ta2*S22;
        double Ub0 = Tb0*S00+Tb1*S01+Tb2*S02;
        double Ub1 = Tb0*S01+Tb1*S11+Tb2*S12;
        double Ub2 = Tb0*S02+Tb1*S12+Tb2*S22;
        double a = Ua0*Ta0+Ua1*Ta1+Ua2*Ta2 + 0.3;
        double b = Ua0*Tb0+Ua1*Tb1+Ua2*Tb2;
        double c = Ub0*Tb0+Ub1*Tb1+Ub2*Tb2 + 0.3;
        double det = a*c - b*b;
        bool valid = (det > 0.0) && (z > 0.2);
        double mid = 0.5 * (a + c);
        double lam = mid + sqrt(fmax(mid*mid - det, 0.1));
        out[3*NPIX + i] = valid ? (float)ceil(3.0 * sqrt(lam)) : 0.0f;
    }

    // ---- P3: fp32 preprocess of ALL gaussians + tile cull (8 iters) ----
    #pragma unroll 2
    for (int it = 0; it < NG / 256; ++it) {
        int gi = it * 256 + tid;
        float m0 = means[3*gi+0], m1 = means[3*gi+1], m2 = means[3*gi+2];
        // fp64 z only for sort key / depth (3 FMAs; preserves proven order)
        double zd = (double)vm4[8]*m0 + (double)vm4[9]*m1 + (double)vm4[10]*m2 + (double)vm4[11];
        float z = (float)zd;
        float x = fR00*m0 + fR01*m1 + fR02*m2 + ft0;
        float y = fR10*m0 + fR11*m1 + fR12*m2 + ft1;
        float zc = fmaxf(z, 1e-4f);
        float invz = 1.0f / zc;
        float tx = fminf(0.65f, fmaxf(-0.65f, x * invz)) * zc;
        float ty = fminf(0.65f, fmaxf(-0.65f, y * invz)) * zc;
        float J00 = 128.f * invz, J02 = -128.f * tx * invz * invz;
        float J11 = 128.f * invz, J12 = -128.f * ty * invz * invz;
        float qw = rots[4*gi+0], qx = rots[4*gi+1], qy = rots[4*gi+2], qz = rots[4*gi+3];
        float qn = 1.0f / sqrtf(qw*qw + qx*qx + qy*qy + qz*qz);
        qw *= qn; qx *= qn; qy *= qn; qz *= qn;
        float Rg00 = 1.f-2.f*(qy*qy+qz*qz), Rg01 = 2.f*(qx*qy-qw*qz), Rg02 = 2.f*(qx*qz+qw*qy);
        float Rg10 = 2.f*(qx*qy+qw*qz), Rg11 = 1.f-2.f*(qx*qx+qz*qz), Rg12 = 2.f*(qy*qz-qw*qx);
        float Rg20 = 2.f*(qx*qz-qw*qy), Rg21 = 2.f*(qy*qz+qw*qx), Rg22 = 1.f-2.f*(qx*qx+qy*qy);
        float s0 = scales[3*gi+0], s1 = scales[3*gi+1], s2 = scales[3*gi+2];
        float M00 = Rg00*s0, M01 = Rg01*s1, M02 = Rg02*s2;
        float M10 = Rg10*s0, M11 = Rg11*s1, M12 = Rg12*s2;
        float M20 = Rg20*s0, M21 = Rg21*s1, M22 = Rg22*s2;
        float S00 = M00*M00+M01*M01+M02*M02;
        float S01 = M00*M10+M01*M11+M02*M12;
        float S02 = M00*M20+M01*M21+M02*M22;
        float S11 = M10*M10+M11*M11+M12*M12;
        float S12 = M10*M20+M11*M21+M12*M22;
        float S22 = M20*M20+M21*M21+M22*M22;
        float Ta0 = J00*fR00+J02*fR20, Ta1 = J00*fR01+J02*fR21, Ta2 = J00*fR02+J02*fR22;
        float Tb0 = J11*fR10+J12*fR20, Tb1 = J11*fR11+J12*fR21, Tb2 = J11*fR12+J12*fR22;
        float Ua0 = Ta0*S00+Ta1*S01+Ta2*S02;
        float Ua1 = Ta0*S01+Ta1*S11+Ta2*S12;
        float Ua2 = Ta0*S02+Ta1*S12+Ta2*S22;
        float Ub0 = Tb0*S00+Tb1*S01+Tb2*S02;
        float Ub1 = Tb0*S01+Tb1*S11+Tb2*S12;
        float Ub2 = Tb0*S02+Tb1*S12+Tb2*S22;
        float a = Ua0*Ta0+Ua1*Ta1+Ua2*Ta2 + 0.3f;
        float b = Ua0*Tb0+Ua1*Tb1+Ua2*Tb2;
        float c = Ub0*Tb0+Ub1*Tb1+Ub2*Tb2 + 0.3f;
        float det = a*c - b*b;
        bool valid = (det > 0.0f) && (z > 0.2f);
        float inv_det = (det != 0.0f) ? (1.0f / det) : 0.0f;
        float mid = 0.5f * (a + c);
        float lam = mid + sqrtf(fmaxf(mid*mid - det, 0.1f));
        float op = valid ? opac[gi] : 0.0f;
        float r2c = -1.0f;
        if (op > 0.0f) {
            float lnterm = __logf(255.f * op);
            if (lnterm > 0.0f) r2c = 2.f * lnterm * lam * 1.001f + 1e-2f;
        }
        float fmx = 128.f * (x * invz) + 63.5f;
        float fmy = 128.f * (y * invz) + 63.5f;
        float ddx = fmaxf(0.f, fmaxf(x0f - fmx, fmx - x1f));
        float ddy = fmaxf(0.f, fmaxf(y0f - fmy, fmy - y1f));
        if (ddx*ddx + ddy*ddy <= r2c) {
            int s = atomicAdd(&cntK, 1);
            if (s < KCAP) {
                recs[s][0] = fmx;
                recs[s][1] = fmy;
                recs[s][2] =  c * inv_det;
                recs[s][3] = -b * inv_det;
                recs[s][4] =  a * inv_det;
                recs[s][5] = op;
                recs[s][6] = z;
                recs[s][7] = cols[3*gi+0];
                recs[s][8] = cols[3*gi+1];
                recs[s][9] = cols[3*gi+2];
                pz[s]  = z;
                pid[s] = (unsigned short)gi;
            }
        }
    }
    __syncthreads();
    int K = min(cntK, KCAP);

    // ---- P4: exact stable rank (z asc, idx asc) + physical reorder ----
    for (int r = tid; r < K; r += 256) {
        float zr = pz[r];
        int ir = pid[r];
        int rank = 0;
        for (int s2 = 0; s2 < K; ++s2)
            rank += (pz[s2] < zr) || (pz[s2] == zr && pid[s2] < ir);
        float4 v0 = ((const float4*)recs[r])[0];
        float4 v1 = ((const float4*)recs[r])[1];
        float4 v2 = ((const float4*)recs[r])[2];
        ((float4*)srec[rank])[0] = v0;
        ((float4*)srec[rank])[1] = v1;
        ((float4*)srec[rank])[2] = v2;
    }
    __syncthreads();

    // ---- P5: 4-wave depth-segment compositing (broadcast b128 reads) ----
    int lane = tid & 63;
    int w    = tid >> 6;
    int px = x0 + (lane & 7);
    int py = y0 + (lane >> 3);
    float fpx = (float)px, fpy = (float)py;
    int p = py * IMG_W + px;

    int q  = (K + 3) >> 2;
    int rs = w * q;
    int re = min(rs + q, K);

    float cr = 0.f, cg = 0.f, cb = 0.f, dep = 0.f, T = 1.f;
    for (int r = rs; r < re; ++r) {
        float4 v0 = ((const float4*)srec[r])[0];   // mx,my,A,B
        float4 v1 = ((const float4*)srec[r])[1];   // C,op,z,colR
        float4 v2 = ((const float4*)srec[r])[2];   // colG,colB,-,-
        float dx = v0.x - fpx;
        float dy = v0.y - fpy;
        float power = -0.5f * (v0.z*dx*dx + v1.x*dy*dy) - v0.w*dx*dy;
        float al = fminf(0.99f, v1.y * __expf(power));
        bool take = (power <= 0.0f) && (al >= (1.0f / 255.0f));
        float wgt = take ? al * T : 0.0f;
        dep += wgt * v1.z;
        cr  += wgt * v1.w;
        cg  += wgt * v2.x;
        cb  += wgt * v2.y;
        if (take) T *= (1.0f - al);
    }

    int cb_base = (w * 64 + lane) * 5;
    comb[cb_base + 0] = cr;
    comb[cb_base + 1] = cg;
    comb[cb_base + 2] = cb;
    comb[cb_base + 3] = dep;
    comb[cb_base + 4] = T;
    __syncthreads();

    if (w == 0) {
        float CR = 0.f, CG = 0.f, CB = 0.f, DEP = 0.f, TT = 1.f;
        #pragma unroll
        for (int ww = 0; ww < 4; ++ww) {
            int b2 = (ww * 64 + lane) * 5;
            CR  += TT * comb[b2 + 0];
            CG  += TT * comb[b2 + 1];
            CB  += TT * comb[b2 + 2];
            DEP += TT * comb[b2 + 3];
            TT  *= comb[b2 + 4];
        }
        out[0*NPIX + p] = CR + TT * bg[0];
        out[1*NPIX + p] = CG + TT * bg[1];
        out[2*NPIX + p] = CB + TT * bg[2];
        out[3*NPIX + NG + p]        = DEP;        // depth
        out[3*NPIX + NG + NPIX + p] = 1.f - TT;   // alpha image
    }
}

extern "C" void kernel_launch(void* const* d_in, const int* in_sizes, int n_in,
                              void* d_out, int out_size, void* d_ws, size_t ws_size,
                              hipStream_t stream)
{
    const float* means = (const float*)d_in[0];
    const float* opac  = (const float*)d_in[1];
    const float* cols  = (const float*)d_in[2];
    const float* scl   = (const float*)d_in[3];
    const float* rot   = (const float*)d_in[4];
    const float* vm    = (const float*)d_in[5];
    const float* bg    = (const float*)d_in[6];
    float* out = (float*)d_out;

    fused_raster_kernel<<<256, 256, 0, stream>>>(
        means, opac, cols, scl, rot, vm, bg, out);
}